// Round 11
// baseline (185.713 us; speedup 1.0000x reference)
//
#include <hip/hip_runtime.h>
#include <stdint.h>

#define NB 1024          // B molecules
#define LMAX 160
#define DIM 128
#define NH 4
#define HDIM 32
#define ATT_SCALE 0.1767766952966369f   // 32^-0.5
#define LN_EPS 1e-5f
#define VTP 164          // V^T LDS pitch (u16)
#define PSP 40           // P LDS pitch (u16)
#define QKP 36           // K/Q LDS pitch (u16): 72B rows, 8B-aligned, ~4-way banks
#define WTP 136          // W^T LDS pitch for out_mfma

typedef __attribute__((ext_vector_type(8))) short bf16x8;
typedef __attribute__((ext_vector_type(4))) float f32x4;

union U8 { uint2 u[2]; uint4 q; bf16x8 v; };

__device__ __forceinline__ ushort f2bf(float f) {
    uint32_t x = __float_as_uint(f);
    x += 0x7fffu + ((x >> 16) & 1u);   // round-to-nearest-even
    return (ushort)(x >> 16);
}
__device__ __forceinline__ uint32_t pk2bf(float a, float b) {
    return (uint32_t)f2bf(a) | ((uint32_t)f2bf(b) << 16);
}

// ---------------------------------------------------------------------------
// K0: segment starts/counts via binary search on the sorted batch arrays.
// ---------------------------------------------------------------------------
__global__ void seg_kernel(const int* __restrict__ bd, const int* __restrict__ ba,
                           int* __restrict__ starts, int* __restrict__ counts, int N)
{
    int t = blockIdx.x * blockDim.x + threadIdx.x;
    if (t >= 2 * NB) return;
    int side = t >> 10;
    int b = t & (NB - 1);
    const int* arr = side ? ba : bd;
    int lo = 0, hi = N;
    while (lo < hi) { int mid = (lo + hi) >> 1; if (arr[mid] < b) lo = mid + 1; else hi = mid; }
    int st = lo;
    hi = N;
    while (lo < hi) { int mid = (lo + hi) >> 1; if (arr[mid] < b + 1) lo = mid + 1; else hi = mid; }
    starts[t] = st;
    counts[t] = lo - st;
}

// ---------------------------------------------------------------------------
// K0b: pre-transpose weights to bf16 [c][k] layout.  m: 0=Wq 1=Wk 2=Wv 3=Wo.
// ---------------------------------------------------------------------------
__global__ void prep_kernel(const float* __restrict__ Wq, const float* __restrict__ Wk,
                            const float* __restrict__ Wv, const float* __restrict__ Wo,
                            ushort* __restrict__ wtg)
{
    int t = blockIdx.x * blockDim.x + threadIdx.x;   // 65536 threads
    int m = t >> 14;
    int idx = t & 16383;
    int k = idx >> 7, c = idx & 127;
    const float* W = (m == 0) ? Wq : (m == 1) ? Wk : (m == 2) ? Wv : Wo;
    wtg[(m << 14) + c * DIM + k] = f2bf(W[idx]);
}

// ---------------------------------------------------------------------------
// proj_tiles: project 16-row x tiles through one W^T head-slice into LDS.
// A = x rows (VERIFIED R9 frag), B = W^T slice from global (VERIFIED R6 frag,
// 8 loads reused across tiles), D scatter = VERIFIED R8 layout
// (row = kg*4+j, col = ct*16+r16).  TR=true writes transposed (for V^T).
// Rows clamped to n-1 (duplicates; masked downstream by index guards).
// ---------------------------------------------------------------------------
template<bool TR>
__device__ __forceinline__ void proj_tiles(
    const float* __restrict__ xrow0, int n, int row0, int ntiles,
    const ushort* __restrict__ wslice, const float* __restrict__ bias,
    int hcol, int r16, int kg, ushort* __restrict__ dst, int pitch)
{
    bf16x8 wb[2][4];
    #pragma unroll
    for (int ct = 0; ct < 2; ++ct)
        #pragma unroll
        for (int ks = 0; ks < 4; ++ks)
            wb[ct][ks] = *reinterpret_cast<const bf16x8*>(
                &wslice[(hcol + ct * 16 + r16) * DIM + ks * 32 + kg * 8]);
    const float b0 = bias[hcol + r16];
    const float b1 = bias[hcol + 16 + r16];

    for (int tr = 0; tr < ntiles; ++tr) {
        int rowc = min(row0 + tr * 16 + r16, n - 1);
        const float* xr = xrow0 + (size_t)rowc * DIM + kg * 8;
        float4 raw[4][2];
        #pragma unroll
        for (int ks = 0; ks < 4; ++ks) {
            raw[ks][0] = *reinterpret_cast<const float4*>(xr + ks * 32);
            raw[ks][1] = *reinterpret_cast<const float4*>(xr + ks * 32 + 4);
        }
        U8 xb[4];
        #pragma unroll
        for (int ks = 0; ks < 4; ++ks) {
            xb[ks].u[0].x = pk2bf(raw[ks][0].x, raw[ks][0].y);
            xb[ks].u[0].y = pk2bf(raw[ks][0].z, raw[ks][0].w);
            xb[ks].u[1].x = pk2bf(raw[ks][1].x, raw[ks][1].y);
            xb[ks].u[1].y = pk2bf(raw[ks][1].z, raw[ks][1].w);
        }
        f32x4 acc0 = {0.f, 0.f, 0.f, 0.f}, acc1 = {0.f, 0.f, 0.f, 0.f};
        #pragma unroll
        for (int ks = 0; ks < 4; ++ks) {
            acc0 = __builtin_amdgcn_mfma_f32_16x16x32_bf16(xb[ks].v, wb[0][ks], acc0, 0, 0, 0);
            acc1 = __builtin_amdgcn_mfma_f32_16x16x32_bf16(xb[ks].v, wb[1][ks], acc1, 0, 0, 0);
        }
        #pragma unroll
        for (int j = 0; j < 4; ++j) {
            int lr = tr * 16 + kg * 4 + j;
            ushort v0 = f2bf(acc0[j] + b0);
            ushort v1 = f2bf(acc1[j] + b1);
            if (TR) {
                dst[(r16) * pitch + lr]      = v0;
                dst[(16 + r16) * pitch + lr] = v1;
            } else {
                dst[lr * pitch + r16]      = v0;
                dst[lr * pitch + 16 + r16] = v1;
            }
        }
    }
}

// ---------------------------------------------------------------------------
// K1: FUSED projection + cross attention.  grid (B, 2, NH), 1 wave/block.
// Each block projects its own Q/K/V head-slices (qkv intermediate eliminated),
// then runs the VERIFIED R4 swapped-operand attention with LDS sources.
// Attended written bf16 to att[(dir*N + row)][hcol..].
// ---------------------------------------------------------------------------
__global__ __launch_bounds__(64) void fused_attn(
    const float* __restrict__ x_don, const float* __restrict__ x_acc,
    const ushort* __restrict__ wtg,
    const float* __restrict__ bq, const float* __restrict__ bk, const float* __restrict__ bv,
    const int* __restrict__ starts, const int* __restrict__ counts,
    ushort* __restrict__ att, int N)
{
    __shared__ __align__(16) ushort Ks[LMAX][QKP];   // K slice, rows = k
    __shared__ __align__(16) ushort Qt[16][QKP];     // Q tile ping (per q0)
    __shared__ __align__(16) ushort Vt[HDIM][VTP];   // V^T slice
    __shared__ __align__(16) ushort Ps[16][PSP];     // P round-trip tile
    const int b = blockIdx.x, dir = blockIdx.y;
    const int hcol = blockIdx.z * HDIM;
    const int qside = dir, kside = 1 - dir;
    const int qs = starts[qside * NB + b];
    const int nq = counts[qside * NB + b];
    if (nq == 0) return;
    const int kst = starts[kside * NB + b];
    const int nk = min(counts[kside * NB + b], LMAX);
    const float* xq = qside ? x_acc : x_don;
    const float* xk = kside ? x_acc : x_don;
    const int lane = threadIdx.x;
    const int r16 = lane & 15, g = lane >> 4;

    const int NCK = (nk + 31) >> 5;                  // 32-k chunks
    const int ntk = (nk + 15) >> 4;                  // K row tiles (clamped reads ok)
    const int ntv = NCK * 2;                         // V^T staged to full NKP cols

    if (nk > 0) {
        proj_tiles<false>(xk + (size_t)kst * DIM, nk, 0, ntk,
                          wtg + (1 << 14), bk, hcol, r16, g, &Ks[0][0], QKP);
        proj_tiles<true >(xk + (size_t)kst * DIM, nk, 0, ntv,
                          wtg + (2 << 14), bv, hcol, r16, g, &Vt[0][0], VTP);
    }
    __syncthreads();

    for (int q0 = 0; q0 < nq; q0 += 16) {
        proj_tiles<false>(xq + (size_t)qs * DIM, nq, q0, 1,
                          wtg, bq, hcol, r16, g, &Qt[0][0], QKP);
        // compiler inserts lgkmcnt for the same-wave LDS RAW (as with Ps in R4)
        bf16x8 bQ = *reinterpret_cast<const bf16x8*>(&Qt[r16][g * 8]);

        float m = -1e30f, l = 0.f;
        f32x4 oa0 = {0.f, 0.f, 0.f, 0.f}, oa1 = {0.f, 0.f, 0.f, 0.f};

        for (int ck = 0; ck < NCK; ++ck) {
            const int k0 = ck * 32;
            const int kr0 = min(k0 + r16, nk - 1);
            const int kr1 = min(k0 + 16 + r16, nk - 1);
            bf16x8 aK0 = *reinterpret_cast<const bf16x8*>(&Ks[kr0][g * 8]);
            bf16x8 aK1 = *reinterpret_cast<const bf16x8*>(&Ks[kr1][g * 8]);
            f32x4 s0 = __builtin_amdgcn_mfma_f32_16x16x32_bf16(
                aK0, bQ, (f32x4){0.f, 0.f, 0.f, 0.f}, 0, 0, 0);
            f32x4 s1 = __builtin_amdgcn_mfma_f32_16x16x32_bf16(
                aK1, bQ, (f32x4){0.f, 0.f, 0.f, 0.f}, 0, 0, 0);

            float sv[8];
            #pragma unroll
            for (int j = 0; j < 4; ++j) {
                sv[j]     = (k0 + 4 * g + j < nk)      ? s0[j] * ATT_SCALE : -1e30f;
                sv[4 + j] = (k0 + 16 + 4 * g + j < nk) ? s1[j] * ATT_SCALE : -1e30f;
            }
            float tm = fmaxf(fmaxf(fmaxf(sv[0], sv[1]), fmaxf(sv[2], sv[3])),
                             fmaxf(fmaxf(sv[4], sv[5]), fmaxf(sv[6], sv[7])));
            tm = fmaxf(tm, __shfl_xor(tm, 16));
            tm = fmaxf(tm, __shfl_xor(tm, 32));

            bool up = tm > m + 8.f;                  // defer-max (T13)
            float mn = up ? tm : m;
            float corr = up ? __expf(m - tm) : 1.f;

            float e[8];
            #pragma unroll
            for (int j = 0; j < 8; ++j) e[j] = __expf(sv[j] - mn);
            float ps = ((e[0] + e[1]) + (e[2] + e[3])) + ((e[4] + e[5]) + (e[6] + e[7]));
            ps += __shfl_xor(ps, 16);
            ps += __shfl_xor(ps, 32);
            l = l * corr + ps;
            m = mn;
            #pragma unroll
            for (int j = 0; j < 4; ++j) { oa0[j] *= corr; oa1[j] *= corr; }

            uint2 w0, w1;
            w0.x = pk2bf(e[0], e[1]);
            w0.y = pk2bf(e[2], e[3]);
            w1.x = pk2bf(e[4], e[5]);
            w1.y = pk2bf(e[6], e[7]);
            *reinterpret_cast<uint2*>(&Ps[r16][4 * g]) = w0;
            *reinterpret_cast<uint2*>(&Ps[r16][16 + 4 * g]) = w1;
            bf16x8 bP = *reinterpret_cast<const bf16x8*>(&Ps[r16][g * 8]);

            U8 av0, av1;
            av0.u[0] = *reinterpret_cast<const uint2*>(&Vt[r16][k0 + g * 8]);
            av0.u[1] = *reinterpret_cast<const uint2*>(&Vt[r16][k0 + g * 8 + 4]);
            av1.u[0] = *reinterpret_cast<const uint2*>(&Vt[16 + r16][k0 + g * 8]);
            av1.u[1] = *reinterpret_cast<const uint2*>(&Vt[16 + r16][k0 + g * 8 + 4]);
            oa0 = __builtin_amdgcn_mfma_f32_16x16x32_bf16(av0.v, bP, oa0, 0, 0, 0);
            oa1 = __builtin_amdgcn_mfma_f32_16x16x32_bf16(av1.v, bP, oa1, 0, 0, 0);
        }

        if (q0 + r16 < nq) {
            float inv = 1.f / fmaxf(l, 1e-9f);
            ushort* dst = &att[((size_t)(dir * N + qs + q0 + r16)) * DIM + hcol];
            uint2 o0, o1;
            o0.x = pk2bf(oa0[0] * inv, oa0[1] * inv);
            o0.y = pk2bf(oa0[2] * inv, oa0[3] * inv);
            o1.x = pk2bf(oa1[0] * inv, oa1[1] * inv);
            o1.y = pk2bf(oa1[2] * inv, oa1[3] * inv);
            *reinterpret_cast<uint2*>(dst + 4 * g) = o0;
            *reinterpret_cast<uint2*>(dst + 16 + 4 * g) = o1;
        }
    }
}

// ---------------------------------------------------------------------------
// K3: MFMA out-projection + bias + residual + LayerNorm (R7-R10 verified;
// only change: attended read from the flat att buffer, rows [0, 2N)).
// ---------------------------------------------------------------------------
__global__ __launch_bounds__(256) void out_mfma(
    const ushort* __restrict__ att,
    const float* __restrict__ x_don, const float* __restrict__ x_acc,
    const ushort* __restrict__ wtg,
    const float* __restrict__ bo, const float* __restrict__ ln_g, const float* __restrict__ ln_b,
    float* __restrict__ out, int N)
{
    __shared__ ushort wt[128][WTP];
    const int t = threadIdx.x;
    const int lane = t & 63, wid = t >> 6;
    const int r16 = lane & 15, kg = lane >> 4;
    const int r0 = blockIdx.x * 128;                 // row in [0, 2N)
    const int wr0 = r0 + wid * 32;
    const float* xresb = (r0 < N) ? x_don : x_acc;
    const int rx0 = (r0 < N) ? wr0 : wr0 - N;

    const ushort* wsrc = wtg + ((size_t)3 << 14);    // Wo^T
    #pragma unroll
    for (int p = 0; p < 8; ++p) {
        int lin = (p * 256 + t) * 8;
        int c = lin >> 7, k = lin & 127;
        *reinterpret_cast<uint4*>(&wt[c][k]) =
            *reinterpret_cast<const uint4*>(&wsrc[c * DIM + k]);
    }

    U8 ab[2][4];                                     // attended A-frags (bf16)
    #pragma unroll
    for (int rt = 0; rt < 2; ++rt)
        #pragma unroll
        for (int ks = 0; ks < 4; ++ks)
            ab[rt][ks].q = *reinterpret_cast<const uint4*>(
                &att[(size_t)(wr0 + rt * 16 + r16) * DIM + ks * 32 + kg * 8]);

    __syncthreads();                                 // wt ready

    f32x4 acc[2][8];
    #pragma unroll
    for (int i = 0; i < 2; ++i)
        #pragma unroll
        for (int j = 0; j < 8; ++j) acc[i][j] = (f32x4){0.f, 0.f, 0.f, 0.f};

    #pragma unroll
    for (int ks = 0; ks < 4; ++ks)
        #pragma unroll
        for (int ct = 0; ct < 8; ++ct) {
            bf16x8 bfr = *reinterpret_cast<const bf16x8*>(
                &wt[ct * 16 + r16][ks * 32 + kg * 8]);
            acc[0][ct] = __builtin_amdgcn_mfma_f32_16x16x32_bf16(ab[0][ks].v, bfr, acc[0][ct], 0, 0, 0);
            acc[1][ct] = __builtin_amdgcn_mfma_f32_16x16x32_bf16(ab[1][ks].v, bfr, acc[1][ct], 0, 0, 0);
        }

    float bo8[8], g8[8], be8[8];
    #pragma unroll
    for (int ct = 0; ct < 8; ++ct) {
        int c = ct * 16 + r16;
        bo8[ct] = bo[c]; g8[ct] = ln_g[c]; be8[ct] = ln_b[c];
    }

    #pragma unroll
    for (int rt = 0; rt < 2; ++rt) {
        #pragma unroll
        for (int j = 0; j < 4; ++j) {
            int rl = rt * 16 + kg * 4 + j;           // VERIFIED: D row -> att-row
            const float* resr = &xresb[(size_t)(rx0 + rl) * DIM];
            float y[8];
            float s = 0.f, ss = 0.f;
            #pragma unroll
            for (int ct = 0; ct < 8; ++ct) {
                float v = acc[rt][ct][j] + bo8[ct] + resr[ct * 16 + r16];
                y[ct] = v; s += v; ss += v * v;
            }
            #pragma unroll
            for (int mk2 = 1; mk2 < 16; mk2 <<= 1) {
                s  += __shfl_xor(s, mk2);
                ss += __shfl_xor(ss, mk2);
            }
            float mu   = s * (1.f / 128.f);
            float var  = ss * (1.f / 128.f) - mu * mu;
            float rinv = rsqrtf(var + LN_EPS);
            #pragma unroll
            for (int ct = 0; ct < 8; ++ct)
                out[(size_t)(wr0 + rl) * DIM + ct * 16 + r16] =
                    (y[ct] - mu) * rinv * g8[ct] + be8[ct];
        }
    }
}

// ---------------------------------------------------------------------------
extern "C" void kernel_launch(void* const* d_in, const int* in_sizes, int n_in,
                              void* d_out, int out_size, void* d_ws, size_t ws_size,
                              hipStream_t stream)
{
    const float* x_don = (const float*)d_in[0];
    const float* x_acc = (const float*)d_in[1];
    const float* Wq = (const float*)d_in[2];  const float* bq = (const float*)d_in[3];
    const float* Wk = (const float*)d_in[4];  const float* bk = (const float*)d_in[5];
    const float* Wv = (const float*)d_in[6];  const float* bv = (const float*)d_in[7];
    const float* Wo = (const float*)d_in[8];  const float* bo = (const float*)d_in[9];
    const float* ln_g = (const float*)d_in[10]; const float* ln_b = (const float*)d_in[11];
    const int* batch_don = (const int*)d_in[12];
    const int* batch_acc = (const int*)d_in[13];
    const int N = in_sizes[0] / DIM;          // 65536
    float* out = (float*)d_out;

    char* ws = (char*)d_ws;
    int* starts = (int*)ws;                           // 2*NB ints
    int* counts = starts + 2 * NB;                    // 2*NB ints
    ushort* wtg = (ushort*)(ws + 16384);              // 4 x 16384 bf16 (128KB)
    ushort* att = (ushort*)(ws + 16384 + 131072);     // 2*N*DIM bf16 (32MB)

    seg_kernel<<<8, 256, 0, stream>>>(batch_don, batch_acc, starts, counts, N);
    prep_kernel<<<256, 256, 0, stream>>>(Wq, Wk, Wv, Wo, wtg);

    dim3 gattn(NB, 2, NH);
    fused_attn<<<gattn, 64, 0, stream>>>(x_don, x_acc, wtg, bq, bk, bv,
                                         starts, counts, att, N);

    out_mfma<<<(2 * N) / 128, 256, 0, stream>>>(att, x_don, x_acc, wtg,
                                                bo, ln_g, ln_b, out, N);
}

// Round 12
// 138.943 us; speedup vs baseline: 1.3366x; 1.3366x over previous
//
#include <hip/hip_runtime.h>
#include <stdint.h>

#define NB 1024          // B molecules
#define LMAX 160
#define DIM 128
#define NH 4
#define HDIM 32
#define ATT_SCALE 0.1767766952966369f   // 32^-0.5
#define LN_EPS 1e-5f
#define VTP 164          // V^T LDS pitch (u16): conflict-free b64 reads
#define PSP 40           // P LDS pitch (u16)
#define WTP 136          // W^T LDS pitch (u16): 272B rows, 16B-aligned, 2-way banks

typedef __attribute__((ext_vector_type(8))) short bf16x8;
typedef __attribute__((ext_vector_type(4))) float f32x4;

union U8 { uint2 u[2]; uint4 q; bf16x8 v; };

__device__ __forceinline__ ushort f2bf(float f) {
    uint32_t x = __float_as_uint(f);
    x += 0x7fffu + ((x >> 16) & 1u);   // round-to-nearest-even
    return (ushort)(x >> 16);
}
__device__ __forceinline__ uint32_t pk2bf(float a, float b) {
    return (uint32_t)f2bf(a) | ((uint32_t)f2bf(b) << 16);
}

// ---------------------------------------------------------------------------
// K0: merged setup.  All 65536 threads transpose weights to bf16 [c][k]
// (m: 0=Wq 1=Wk 2=Wv 3=Wo); threads < 2048 additionally compute segment
// starts/counts via binary search on the sorted batch arrays.  One launch
// instead of two (independent outputs).
// ---------------------------------------------------------------------------
__global__ void setup_kernel(const float* __restrict__ Wq, const float* __restrict__ Wk,
                             const float* __restrict__ Wv, const float* __restrict__ Wo,
                             ushort* __restrict__ wtg,
                             const int* __restrict__ bd, const int* __restrict__ ba,
                             int* __restrict__ starts, int* __restrict__ counts, int N)
{
    int t = blockIdx.x * blockDim.x + threadIdx.x;   // 65536 threads
    {   // weight transpose (all threads)
        int m = t >> 14;
        int idx = t & 16383;
        int k = idx >> 7, c = idx & 127;
        const float* W = (m == 0) ? Wq : (m == 1) ? Wk : (m == 2) ? Wv : Wo;
        wtg[(m << 14) + c * DIM + k] = f2bf(W[idx]);
    }
    if (t < 2 * NB) {    // segment search (first 2048 threads)
        int side = t >> 10;
        int b = t & (NB - 1);
        const int* arr = side ? ba : bd;
        int lo = 0, hi = N;
        while (lo < hi) { int mid = (lo + hi) >> 1; if (arr[mid] < b) lo = mid + 1; else hi = mid; }
        int st = lo;
        hi = N;
        while (lo < hi) { int mid = (lo + hi) >> 1; if (arr[mid] < b + 1) lo = mid + 1; else hi = mid; }
        starts[t] = st;
        counts[t] = lo - st;
    }
}

// ---------------------------------------------------------------------------
// K1: MFMA projections (R9-verified structure, 140.6us build).  w-loop inside
// the block (x read once); x loads issued as a full batch of 16 float4 into
// named registers, then converted; W^T staged per-w into one 34.8KB LDS
// buffer (4 blocks/CU).  VERIFIED routing + epilogue.
// ---------------------------------------------------------------------------
__global__ __launch_bounds__(256) void proj_mfma(
    const float* __restrict__ x_don, const float* __restrict__ x_acc,
    const ushort* __restrict__ wtg,
    const float* __restrict__ bq, const float* __restrict__ bk, const float* __restrict__ bv,
    ushort* __restrict__ qkv, int N)
{
    __shared__ ushort wt[128][WTP];
    const int side = blockIdx.y;
    const float* x = side ? x_acc : x_don;
    const int t = threadIdx.x;
    const int lane = t & 63, wid = t >> 6;
    const int r16 = lane & 15, kg = lane >> 4;
    const int wr0 = blockIdx.x * 128 + wid * 32;     // this wave's first row

    // ---- batched x loads: ALL 16 float4 in flight, then convert
    float4 raw[2][4][2];
    #pragma unroll
    for (int rt = 0; rt < 2; ++rt) {
        const float* xr = &x[(size_t)(wr0 + rt * 16 + r16) * DIM + kg * 8];
        #pragma unroll
        for (int ks = 0; ks < 4; ++ks) {
            raw[rt][ks][0] = *reinterpret_cast<const float4*>(xr + ks * 32);
            raw[rt][ks][1] = *reinterpret_cast<const float4*>(xr + ks * 32 + 4);
        }
    }
    U8 xb[2][4];
    #pragma unroll
    for (int rt = 0; rt < 2; ++rt)
        #pragma unroll
        for (int ks = 0; ks < 4; ++ks) {
            xb[rt][ks].u[0].x = pk2bf(raw[rt][ks][0].x, raw[rt][ks][0].y);
            xb[rt][ks].u[0].y = pk2bf(raw[rt][ks][0].z, raw[rt][ks][0].w);
            xb[rt][ks].u[1].x = pk2bf(raw[rt][ks][1].x, raw[rt][ks][1].y);
            xb[rt][ks].u[1].y = pk2bf(raw[rt][ks][1].z, raw[rt][ks][1].w);
        }

    for (int w = 0; w < 3; ++w) {
        if (w) __syncthreads();                      // prior w's LDS reads done
        const ushort* wsrc = wtg + ((size_t)w << 14);
        #pragma unroll
        for (int p = 0; p < 8; ++p) {
            int lin = (p * 256 + t) * 8;
            int c = lin >> 7, k = lin & 127;
            *reinterpret_cast<uint4*>(&wt[c][k]) =
                *reinterpret_cast<const uint4*>(&wsrc[c * DIM + k]);
        }
        __syncthreads();                             // wt ready

        f32x4 acc[2][8];
        #pragma unroll
        for (int i = 0; i < 2; ++i)
            #pragma unroll
            for (int j = 0; j < 8; ++j) acc[i][j] = (f32x4){0.f, 0.f, 0.f, 0.f};

        #pragma unroll
        for (int ks = 0; ks < 4; ++ks)
            #pragma unroll
            for (int ct = 0; ct < 8; ++ct) {
                bf16x8 bfr = *reinterpret_cast<const bf16x8*>(
                    &wt[ct * 16 + r16][ks * 32 + kg * 8]);
                acc[0][ct] = __builtin_amdgcn_mfma_f32_16x16x32_bf16(xb[0][ks].v, bfr, acc[0][ct], 0, 0, 0);
                acc[1][ct] = __builtin_amdgcn_mfma_f32_16x16x32_bf16(xb[1][ks].v, bfr, acc[1][ct], 0, 0, 0);
            }

        // VERIFIED epilogue: D row=(kg*4+j) -> x-row, col=ct*16+r16 -> out-col
        const float* bias = (w == 0) ? bq : (w == 1) ? bk : bv;
        float b8[8];
        #pragma unroll
        for (int ct = 0; ct < 8; ++ct) b8[ct] = bias[ct * 16 + r16];
        ushort* outp = qkv + (size_t)(side * 3 + w) * N * DIM;
        #pragma unroll
        for (int rt = 0; rt < 2; ++rt)
            #pragma unroll
            for (int ct = 0; ct < 8; ++ct)
                #pragma unroll
                for (int j = 0; j < 4; ++j) {
                    int rr = wr0 + rt * 16 + kg * 4 + j;
                    outp[(size_t)rr * DIM + ct * 16 + r16] = f2bf(acc[rt][ct][j] + b8[ct]);
                }
    }
}

// ---------------------------------------------------------------------------
// K2: swapped-operand MFMA cross attention (unchanged, verified in R4).
// ---------------------------------------------------------------------------
__global__ __launch_bounds__(64, 4) void attn_mfma(
    ushort* __restrict__ qkv,
    const int* __restrict__ starts, const int* __restrict__ counts, int N)
{
    __shared__ __align__(16) ushort Vt[HDIM][VTP];   // V^T slice for this head
    __shared__ __align__(16) ushort Ps[16][PSP];     // P round-trip tile
    const int b = blockIdx.x, dir = blockIdx.y;
    const int hcol = blockIdx.z * HDIM;
    const int qside = dir, kside = 1 - dir;
    const int qs = starts[qside * NB + b];
    const int nq = counts[qside * NB + b];
    if (nq == 0) return;
    const int kst = starts[kside * NB + b];
    const int nk = min(counts[kside * NB + b], LMAX);
    ushort* Q = qkv + (size_t)(qside * 3) * N * DIM;
    const ushort* K = qkv + (size_t)(kside * 3 + 1) * N * DIM;
    const ushort* V = qkv + (size_t)(kside * 3 + 2) * N * DIM;
    const int lane = threadIdx.x;
    const int r16 = lane & 15, g = lane >> 4;

    const int NCK = (nk + 31) >> 5;
    const int NKP = NCK << 5;

    {
        const int krl = lane >> 2, c = lane & 3;
        for (int base = 0; base < nk; base += 16) {
            int kr = base + krl;
            if (kr < nk) {
                uint4 v4 = *reinterpret_cast<const uint4*>(
                    &V[(size_t)(kst + kr) * DIM + hcol + c * 8]);
                uint32_t vv[4] = {v4.x, v4.y, v4.z, v4.w};
                #pragma unroll
                for (int m2 = 0; m2 < 4; ++m2) {
                    Vt[c * 8 + 2 * m2][kr]     = (ushort)(vv[m2] & 0xffffu);
                    Vt[c * 8 + 2 * m2 + 1][kr] = (ushort)(vv[m2] >> 16);
                }
            }
        }
        int pad = NKP - nk;
        for (int i = lane; i < (pad << 5); i += 64) {
            int d = i & 31, col = nk + (i >> 5);
            Vt[d][col] = 0;
        }
    }
    __syncthreads();

    for (int q0 = 0; q0 < nq; q0 += 16) {
        const int rq = qs + min(q0 + r16, nq - 1);
        bf16x8 bQ = *reinterpret_cast<const bf16x8*>(&Q[(size_t)rq * DIM + hcol + g * 8]);

        float m = -1e30f, l = 0.f;
        f32x4 oa0 = {0.f, 0.f, 0.f, 0.f}, oa1 = {0.f, 0.f, 0.f, 0.f};

        for (int ck = 0; ck < NCK; ++ck) {
            const int k0 = ck * 32;
            const int rk0 = kst + min(k0 + r16, nk - 1);
            const int rk1 = kst + min(k0 + 16 + r16, nk - 1);
            bf16x8 aK0 = *reinterpret_cast<const bf16x8*>(&K[(size_t)rk0 * DIM + hcol + g * 8]);
            bf16x8 aK1 = *reinterpret_cast<const bf16x8*>(&K[(size_t)rk1 * DIM + hcol + g * 8]);
            f32x4 s0 = __builtin_amdgcn_mfma_f32_16x16x32_bf16(
                aK0, bQ, (f32x4){0.f, 0.f, 0.f, 0.f}, 0, 0, 0);
            f32x4 s1 = __builtin_amdgcn_mfma_f32_16x16x32_bf16(
                aK1, bQ, (f32x4){0.f, 0.f, 0.f, 0.f}, 0, 0, 0);

            float sv[8];
            #pragma unroll
            for (int j = 0; j < 4; ++j) {
                sv[j]     = (k0 + 4 * g + j < nk)      ? s0[j] * ATT_SCALE : -1e30f;
                sv[4 + j] = (k0 + 16 + 4 * g + j < nk) ? s1[j] * ATT_SCALE : -1e30f;
            }
            float tm = fmaxf(fmaxf(fmaxf(sv[0], sv[1]), fmaxf(sv[2], sv[3])),
                             fmaxf(fmaxf(sv[4], sv[5]), fmaxf(sv[6], sv[7])));
            tm = fmaxf(tm, __shfl_xor(tm, 16));
            tm = fmaxf(tm, __shfl_xor(tm, 32));

            bool up = tm > m + 8.f;                  // defer-max (T13)
            float mn = up ? tm : m;
            float corr = up ? __expf(m - tm) : 1.f;

            float e[8];
            #pragma unroll
            for (int j = 0; j < 8; ++j) e[j] = __expf(sv[j] - mn);
            float ps = ((e[0] + e[1]) + (e[2] + e[3])) + ((e[4] + e[5]) + (e[6] + e[7]));
            ps += __shfl_xor(ps, 16);
            ps += __shfl_xor(ps, 32);
            l = l * corr + ps;
            m = mn;
            #pragma unroll
            for (int j = 0; j < 4; ++j) { oa0[j] *= corr; oa1[j] *= corr; }

            uint2 w0, w1;
            w0.x = pk2bf(e[0], e[1]);
            w0.y = pk2bf(e[2], e[3]);
            w1.x = pk2bf(e[4], e[5]);
            w1.y = pk2bf(e[6], e[7]);
            *reinterpret_cast<uint2*>(&Ps[r16][4 * g]) = w0;
            *reinterpret_cast<uint2*>(&Ps[r16][16 + 4 * g]) = w1;
            bf16x8 bP = *reinterpret_cast<const bf16x8*>(&Ps[r16][g * 8]);

            U8 av0, av1;
            av0.u[0] = *reinterpret_cast<const uint2*>(&Vt[r16][k0 + g * 8]);
            av0.u[1] = *reinterpret_cast<const uint2*>(&Vt[r16][k0 + g * 8 + 4]);
            av1.u[0] = *reinterpret_cast<const uint2*>(&Vt[16 + r16][k0 + g * 8]);
            av1.u[1] = *reinterpret_cast<const uint2*>(&Vt[16 + r16][k0 + g * 8 + 4]);
            oa0 = __builtin_amdgcn_mfma_f32_16x16x32_bf16(av0.v, bP, oa0, 0, 0, 0);
            oa1 = __builtin_amdgcn_mfma_f32_16x16x32_bf16(av1.v, bP, oa1, 0, 0, 0);
        }

        if (q0 + r16 < nq) {
            float inv = 1.f / fmaxf(l, 1e-9f);
            ushort* dst = &Q[(size_t)(qs + q0 + r16) * DIM + hcol];
            uint2 o0, o1;
            o0.x = pk2bf(oa0[0] * inv, oa0[1] * inv);
            o0.y = pk2bf(oa0[2] * inv, oa0[3] * inv);
            o1.x = pk2bf(oa1[0] * inv, oa1[1] * inv);
            o1.y = pk2bf(oa1[2] * inv, oa1[3] * inv);
            *reinterpret_cast<uint2*>(dst + 4 * g) = o0;
            *reinterpret_cast<uint2*>(dst + 16 + 4 * g) = o1;
        }
    }
}

// ---------------------------------------------------------------------------
// K3: MFMA out-projection + bias + residual + LayerNorm (unchanged from R7-R9).
// ---------------------------------------------------------------------------
__global__ __launch_bounds__(256) void out_mfma(
    const ushort* __restrict__ qkv,
    const float* __restrict__ x_don, const float* __restrict__ x_acc,
    const ushort* __restrict__ wtg,
    const float* __restrict__ bo, const float* __restrict__ ln_g, const float* __restrict__ ln_b,
    float* __restrict__ out, int N)
{
    __shared__ ushort wt[128][WTP];
    const int t = threadIdx.x;
    const int lane = t & 63, wid = t >> 6;
    const int r16 = lane & 15, kg = lane >> 4;
    const int r0 = blockIdx.x * 128;                 // row in [0, 2N)
    const int wr0 = r0 + wid * 32;
    const ushort* attb = qkv + (r0 < N ? (size_t)0 : (size_t)2 * N * DIM); // slot0/slot3
    const float* xresb = (r0 < N) ? x_don : x_acc;
    const int rx0 = (r0 < N) ? wr0 : wr0 - N;        // this wave's residual base row

    // ---- stage Wo^T into LDS
    const ushort* wsrc = wtg + ((size_t)3 << 14);
    #pragma unroll
    for (int p = 0; p < 8; ++p) {
        int lin = (p * 256 + t) * 8;
        int c = lin >> 7, k = lin & 127;
        *reinterpret_cast<uint4*>(&wt[c][k]) =
            *reinterpret_cast<const uint4*>(&wsrc[c * DIM + k]);
    }

    // ---- attended A-frags (already bf16), per-lane private
    U8 ab[2][4];
    #pragma unroll
    for (int rt = 0; rt < 2; ++rt)
        #pragma unroll
        for (int ks = 0; ks < 4; ++ks)
            ab[rt][ks].q = *reinterpret_cast<const uint4*>(
                &attb[(size_t)(wr0 + rt * 16 + r16) * DIM + ks * 32 + kg * 8]);

    __syncthreads();                                 // wt ready

    f32x4 acc[2][8];
    #pragma unroll
    for (int i = 0; i < 2; ++i)
        #pragma unroll
        for (int j = 0; j < 8; ++j) acc[i][j] = (f32x4){0.f, 0.f, 0.f, 0.f};

    #pragma unroll
    for (int ks = 0; ks < 4; ++ks)
        #pragma unroll
        for (int ct = 0; ct < 8; ++ct) {
            bf16x8 bfr = *reinterpret_cast<const bf16x8*>(
                &wt[ct * 16 + r16][ks * 32 + kg * 8]);
            acc[0][ct] = __builtin_amdgcn_mfma_f32_16x16x32_bf16(ab[0][ks].v, bfr, acc[0][ct], 0, 0, 0);
            acc[1][ct] = __builtin_amdgcn_mfma_f32_16x16x32_bf16(ab[1][ks].v, bfr, acc[1][ct], 0, 0, 0);
        }

    float bo8[8], g8[8], be8[8];
    #pragma unroll
    for (int ct = 0; ct < 8; ++ct) {
        int c = ct * 16 + r16;
        bo8[ct] = bo[c]; g8[ct] = ln_g[c]; be8[ct] = ln_b[c];
    }

    #pragma unroll
    for (int rt = 0; rt < 2; ++rt) {
        #pragma unroll
        for (int j = 0; j < 4; ++j) {
            int rl = rt * 16 + kg * 4 + j;           // VERIFIED: D row -> att-row (wave-local)
            const float* resr = &xresb[(size_t)(rx0 + rl) * DIM];
            float y[8];
            float s = 0.f, ss = 0.f;
            #pragma unroll
            for (int ct = 0; ct < 8; ++ct) {
                float v = acc[rt][ct][j] + bo8[ct] + resr[ct * 16 + r16];
                y[ct] = v; s += v; ss += v * v;
            }
            #pragma unroll
            for (int mk2 = 1; mk2 < 16; mk2 <<= 1) {
                s  += __shfl_xor(s, mk2);
                ss += __shfl_xor(ss, mk2);
            }
            float mu   = s * (1.f / 128.f);
            float var  = ss * (1.f / 128.f) - mu * mu;
            float rinv = rsqrtf(var + LN_EPS);
            #pragma unroll
            for (int ct = 0; ct < 8; ++ct)
                out[(size_t)(wr0 + rl) * DIM + ct * 16 + r16] =
                    (y[ct] - mu) * rinv * g8[ct] + be8[ct];
        }
    }
}

// ---------------------------------------------------------------------------
extern "C" void kernel_launch(void* const* d_in, const int* in_sizes, int n_in,
                              void* d_out, int out_size, void* d_ws, size_t ws_size,
                              hipStream_t stream)
{
    const float* x_don = (const float*)d_in[0];
    const float* x_acc = (const float*)d_in[1];
    const float* Wq = (const float*)d_in[2];  const float* bq = (const float*)d_in[3];
    const float* Wk = (const float*)d_in[4];  const float* bk = (const float*)d_in[5];
    const float* Wv = (const float*)d_in[6];  const float* bv = (const float*)d_in[7];
    const float* Wo = (const float*)d_in[8];  const float* bo = (const float*)d_in[9];
    const float* ln_g = (const float*)d_in[10]; const float* ln_b = (const float*)d_in[11];
    const int* batch_don = (const int*)d_in[12];
    const int* batch_acc = (const int*)d_in[13];
    const int N = in_sizes[0] / DIM;          // 65536
    float* out = (float*)d_out;

    char* ws = (char*)d_ws;
    int* starts = (int*)ws;                           // 2*NB ints
    int* counts = starts + 2 * NB;                    // 2*NB ints
    ushort* qkv = (ushort*)(ws + 16384);              // 6 x N*DIM bf16 (96MB)
    ushort* wtg = (ushort*)(ws + 16384 + (size_t)6 * N * DIM * 2);  // 4 x 16384 bf16

    setup_kernel<<<256, 256, 0, stream>>>(Wq, Wk, Wv, Wo, wtg,
                                          batch_don, batch_acc, starts, counts, N);

    dim3 gproj(N / 128, 2);
    proj_mfma<<<gproj, 256, 0, stream>>>(x_don, x_acc, wtg, bq, bk, bv, qkv, N);

    dim3 gattn(NB, 2, NH);
    attn_mfma<<<gattn, 64, 0, stream>>>(qkv, starts, counts, N);

    out_mfma<<<(2 * N) / 128, 256, 0, stream>>>(qkv, x_don, x_acc, wtg,
                                                bo, ln_g, ln_b, out, N);
}

// Round 13
// 138.023 us; speedup vs baseline: 1.3455x; 1.0067x over previous
//
#include <hip/hip_runtime.h>
#include <stdint.h>

#define NB 1024          // B molecules
#define LMAX 160
#define DIM 128
#define NH 4
#define HDIM 32
#define ATT_SCALE 0.1767766952966369f   // 32^-0.5
#define LN_EPS 1e-5f
#define VTP 164          // V^T LDS pitch (u16): conflict-free b64 reads
#define PSP 40           // P LDS pitch (u16)
#define WTP 136          // W^T LDS pitch (u16): 272B rows, 16B-aligned, 2-way banks

typedef __attribute__((ext_vector_type(8))) short bf16x8;
typedef __attribute__((ext_vector_type(4))) float f32x4;

union U8 { uint2 u[2]; uint4 q; bf16x8 v; };

__device__ __forceinline__ ushort f2bf(float f) {
    uint32_t x = __float_as_uint(f);
    x += 0x7fffu + ((x >> 16) & 1u);   // round-to-nearest-even
    return (ushort)(x >> 16);
}
__device__ __forceinline__ uint32_t pk2bf(float a, float b) {
    return (uint32_t)f2bf(a) | ((uint32_t)f2bf(b) << 16);
}

// Workgroup barrier WITHOUT the vmcnt(0) store drain __syncthreads would emit.
// lgkmcnt(0) settles this wave's LDS traffic; outstanding GLOBAL STORES (which
// have no intra-kernel consumer) stay in flight across the barrier.  The
// "memory" clobbers pin LDS ops on their side of the barrier.
__device__ __forceinline__ void wgbar_noflush() {
    asm volatile("s_waitcnt lgkmcnt(0)" ::: "memory");
    __builtin_amdgcn_s_barrier();
    asm volatile("" ::: "memory");
}

// ---------------------------------------------------------------------------
// K0: merged setup (weights transpose + segment binary search).
// ---------------------------------------------------------------------------
__global__ void setup_kernel(const float* __restrict__ Wq, const float* __restrict__ Wk,
                             const float* __restrict__ Wv, const float* __restrict__ Wo,
                             ushort* __restrict__ wtg,
                             const int* __restrict__ bd, const int* __restrict__ ba,
                             int* __restrict__ starts, int* __restrict__ counts, int N)
{
    int t = blockIdx.x * blockDim.x + threadIdx.x;   // 65536 threads
    {   // weight transpose (all threads)
        int m = t >> 14;
        int idx = t & 16383;
        int k = idx >> 7, c = idx & 127;
        const float* W = (m == 0) ? Wq : (m == 1) ? Wk : (m == 2) ? Wv : Wo;
        wtg[(m << 14) + c * DIM + k] = f2bf(W[idx]);
    }
    if (t < 2 * NB) {    // segment search (first 2048 threads)
        int side = t >> 10;
        int b = t & (NB - 1);
        const int* arr = side ? ba : bd;
        int lo = 0, hi = N;
        while (lo < hi) { int mid = (lo + hi) >> 1; if (arr[mid] < b) lo = mid + 1; else hi = mid; }
        int st = lo;
        hi = N;
        while (lo < hi) { int mid = (lo + hi) >> 1; if (arr[mid] < b + 1) lo = mid + 1; else hi = mid; }
        starts[t] = st;
        counts[t] = lo - st;
    }
}

// ---------------------------------------------------------------------------
// K1: MFMA projections (R9/R12-verified structure) with NO-FLUSH barriers:
// the w-loop's syncs no longer drain the 64 HBM stores per wave, so the
// write stream pipelines across the whole kernel instead of stalling all
// waves at each barrier.  Routing/epilogue byte-identical to R12.
// ---------------------------------------------------------------------------
__global__ __launch_bounds__(256) void proj_mfma(
    const float* __restrict__ x_don, const float* __restrict__ x_acc,
    const ushort* __restrict__ wtg,
    const float* __restrict__ bq, const float* __restrict__ bk, const float* __restrict__ bv,
    ushort* __restrict__ qkv, int N)
{
    __shared__ ushort wt[128][WTP];
    const int side = blockIdx.y;
    const float* x = side ? x_acc : x_don;
    const int t = threadIdx.x;
    const int lane = t & 63, wid = t >> 6;
    const int r16 = lane & 15, kg = lane >> 4;
    const int wr0 = blockIdx.x * 128 + wid * 32;     // this wave's first row

    // ---- batched x loads: ALL 16 float4 in flight, then convert
    float4 raw[2][4][2];
    #pragma unroll
    for (int rt = 0; rt < 2; ++rt) {
        const float* xr = &x[(size_t)(wr0 + rt * 16 + r16) * DIM + kg * 8];
        #pragma unroll
        for (int ks = 0; ks < 4; ++ks) {
            raw[rt][ks][0] = *reinterpret_cast<const float4*>(xr + ks * 32);
            raw[rt][ks][1] = *reinterpret_cast<const float4*>(xr + ks * 32 + 4);
        }
    }
    U8 xb[2][4];
    #pragma unroll
    for (int rt = 0; rt < 2; ++rt)
        #pragma unroll
        for (int ks = 0; ks < 4; ++ks) {
            xb[rt][ks].u[0].x = pk2bf(raw[rt][ks][0].x, raw[rt][ks][0].y);
            xb[rt][ks].u[0].y = pk2bf(raw[rt][ks][0].z, raw[rt][ks][0].w);
            xb[rt][ks].u[1].x = pk2bf(raw[rt][ks][1].x, raw[rt][ks][1].y);
            xb[rt][ks].u[1].y = pk2bf(raw[rt][ks][1].z, raw[rt][ks][1].w);
        }

    for (int w = 0; w < 3; ++w) {
        // Entry barrier: all waves done READING wt (their frag ds_reads were
        // consumed by MFMAs before reaching here).  Stores from w-1 keep flying.
        if (w) wgbar_noflush();

        const ushort* wsrc = wtg + ((size_t)w << 14);
        #pragma unroll
        for (int p = 0; p < 8; ++p) {
            int lin = (p * 256 + t) * 8;
            int c = lin >> 7, k = lin & 127;
            *reinterpret_cast<uint4*>(&wt[c][k]) =
                *reinterpret_cast<const uint4*>(&wsrc[c * DIM + k]);
        }
        // Staging barrier: lgkmcnt(0) settles this wave's ds_writes (their
        // source VGPRs already vmcnt-waited by the compiler).  No store drain.
        wgbar_noflush();

        f32x4 acc[2][8];
        #pragma unroll
        for (int i = 0; i < 2; ++i)
            #pragma unroll
            for (int j = 0; j < 8; ++j) acc[i][j] = (f32x4){0.f, 0.f, 0.f, 0.f};

        #pragma unroll
        for (int ks = 0; ks < 4; ++ks)
            #pragma unroll
            for (int ct = 0; ct < 8; ++ct) {
                bf16x8 bfr = *reinterpret_cast<const bf16x8*>(
                    &wt[ct * 16 + r16][ks * 32 + kg * 8]);
                acc[0][ct] = __builtin_amdgcn_mfma_f32_16x16x32_bf16(xb[0][ks].v, bfr, acc[0][ct], 0, 0, 0);
                acc[1][ct] = __builtin_amdgcn_mfma_f32_16x16x32_bf16(xb[1][ks].v, bfr, acc[1][ct], 0, 0, 0);
            }

        // VERIFIED epilogue: D row=(kg*4+j) -> x-row, col=ct*16+r16 -> out-col
        const float* bias = (w == 0) ? bq : (w == 1) ? bk : bv;
        float b8[8];
        #pragma unroll
        for (int ct = 0; ct < 8; ++ct) b8[ct] = bias[ct * 16 + r16];
        ushort* outp = qkv + (size_t)(side * 3 + w) * N * DIM;
        #pragma unroll
        for (int rt = 0; rt < 2; ++rt)
            #pragma unroll
            for (int ct = 0; ct < 8; ++ct)
                #pragma unroll
                for (int j = 0; j < 4; ++j) {
                    int rr = wr0 + rt * 16 + kg * 4 + j;
                    outp[(size_t)rr * DIM + ct * 16 + r16] = f2bf(acc[rt][ct][j] + b8[ct]);
                }
        // no trailing barrier: stores drain during the next w's staging/compute
        // (no intra-kernel consumer; kernel end is a system-scope release)
    }
}

// ---------------------------------------------------------------------------
// K2: swapped-operand MFMA cross attention (unchanged, verified in R4).
// ---------------------------------------------------------------------------
__global__ __launch_bounds__(64, 4) void attn_mfma(
    ushort* __restrict__ qkv,
    const int* __restrict__ starts, const int* __restrict__ counts, int N)
{
    __shared__ __align__(16) ushort Vt[HDIM][VTP];   // V^T slice for this head
    __shared__ __align__(16) ushort Ps[16][PSP];     // P round-trip tile
    const int b = blockIdx.x, dir = blockIdx.y;
    const int hcol = blockIdx.z * HDIM;
    const int qside = dir, kside = 1 - dir;
    const int qs = starts[qside * NB + b];
    const int nq = counts[qside * NB + b];
    if (nq == 0) return;
    const int kst = starts[kside * NB + b];
    const int nk = min(counts[kside * NB + b], LMAX);
    ushort* Q = qkv + (size_t)(qside * 3) * N * DIM;
    const ushort* K = qkv + (size_t)(kside * 3 + 1) * N * DIM;
    const ushort* V = qkv + (size_t)(kside * 3 + 2) * N * DIM;
    const int lane = threadIdx.x;
    const int r16 = lane & 15, g = lane >> 4;

    const int NCK = (nk + 31) >> 5;
    const int NKP = NCK << 5;

    {
        const int krl = lane >> 2, c = lane & 3;
        for (int base = 0; base < nk; base += 16) {
            int kr = base + krl;
            if (kr < nk) {
                uint4 v4 = *reinterpret_cast<const uint4*>(
                    &V[(size_t)(kst + kr) * DIM + hcol + c * 8]);
                uint32_t vv[4] = {v4.x, v4.y, v4.z, v4.w};
                #pragma unroll
                for (int m2 = 0; m2 < 4; ++m2) {
                    Vt[c * 8 + 2 * m2][kr]     = (ushort)(vv[m2] & 0xffffu);
                    Vt[c * 8 + 2 * m2 + 1][kr] = (ushort)(vv[m2] >> 16);
                }
            }
        }
        int pad = NKP - nk;
        for (int i = lane; i < (pad << 5); i += 64) {
            int d = i & 31, col = nk + (i >> 5);
            Vt[d][col] = 0;
        }
    }
    __syncthreads();

    for (int q0 = 0; q0 < nq; q0 += 16) {
        const int rq = qs + min(q0 + r16, nq - 1);
        bf16x8 bQ = *reinterpret_cast<const bf16x8*>(&Q[(size_t)rq * DIM + hcol + g * 8]);

        float m = -1e30f, l = 0.f;
        f32x4 oa0 = {0.f, 0.f, 0.f, 0.f}, oa1 = {0.f, 0.f, 0.f, 0.f};

        for (int ck = 0; ck < NCK; ++ck) {
            const int k0 = ck * 32;
            const int rk0 = kst + min(k0 + r16, nk - 1);
            const int rk1 = kst + min(k0 + 16 + r16, nk - 1);
            bf16x8 aK0 = *reinterpret_cast<const bf16x8*>(&K[(size_t)rk0 * DIM + hcol + g * 8]);
            bf16x8 aK1 = *reinterpret_cast<const bf16x8*>(&K[(size_t)rk1 * DIM + hcol + g * 8]);
            f32x4 s0 = __builtin_amdgcn_mfma_f32_16x16x32_bf16(
                aK0, bQ, (f32x4){0.f, 0.f, 0.f, 0.f}, 0, 0, 0);
            f32x4 s1 = __builtin_amdgcn_mfma_f32_16x16x32_bf16(
                aK1, bQ, (f32x4){0.f, 0.f, 0.f, 0.f}, 0, 0, 0);

            float sv[8];
            #pragma unroll
            for (int j = 0; j < 4; ++j) {
                sv[j]     = (k0 + 4 * g + j < nk)      ? s0[j] * ATT_SCALE : -1e30f;
                sv[4 + j] = (k0 + 16 + 4 * g + j < nk) ? s1[j] * ATT_SCALE : -1e30f;
            }
            float tm = fmaxf(fmaxf(fmaxf(sv[0], sv[1]), fmaxf(sv[2], sv[3])),
                             fmaxf(fmaxf(sv[4], sv[5]), fmaxf(sv[6], sv[7])));
            tm = fmaxf(tm, __shfl_xor(tm, 16));
            tm = fmaxf(tm, __shfl_xor(tm, 32));

            bool up = tm > m + 8.f;                  // defer-max (T13)
            float mn = up ? tm : m;
            float corr = up ? __expf(m - tm) : 1.f;

            float e[8];
            #pragma unroll
            for (int j = 0; j < 8; ++j) e[j] = __expf(sv[j] - mn);
            float ps = ((e[0] + e[1]) + (e[2] + e[3])) + ((e[4] + e[5]) + (e[6] + e[7]));
            ps += __shfl_xor(ps, 16);
            ps += __shfl_xor(ps, 32);
            l = l * corr + ps;
            m = mn;
            #pragma unroll
            for (int j = 0; j < 4; ++j) { oa0[j] *= corr; oa1[j] *= corr; }

            uint2 w0, w1;
            w0.x = pk2bf(e[0], e[1]);
            w0.y = pk2bf(e[2], e[3]);
            w1.x = pk2bf(e[4], e[5]);
            w1.y = pk2bf(e[6], e[7]);
            *reinterpret_cast<uint2*>(&Ps[r16][4 * g]) = w0;
            *reinterpret_cast<uint2*>(&Ps[r16][16 + 4 * g]) = w1;
            bf16x8 bP = *reinterpret_cast<const bf16x8*>(&Ps[r16][g * 8]);

            U8 av0, av1;
            av0.u[0] = *reinterpret_cast<const uint2*>(&Vt[r16][k0 + g * 8]);
            av0.u[1] = *reinterpret_cast<const uint2*>(&Vt[r16][k0 + g * 8 + 4]);
            av1.u[0] = *reinterpret_cast<const uint2*>(&Vt[16 + r16][k0 + g * 8]);
            av1.u[1] = *reinterpret_cast<const uint2*>(&Vt[16 + r16][k0 + g * 8 + 4]);
            oa0 = __builtin_amdgcn_mfma_f32_16x16x32_bf16(av0.v, bP, oa0, 0, 0, 0);
            oa1 = __builtin_amdgcn_mfma_f32_16x16x32_bf16(av1.v, bP, oa1, 0, 0, 0);
        }

        if (q0 + r16 < nq) {
            float inv = 1.f / fmaxf(l, 1e-9f);
            ushort* dst = &Q[(size_t)(qs + q0 + r16) * DIM + hcol];
            uint2 o0, o1;
            o0.x = pk2bf(oa0[0] * inv, oa0[1] * inv);
            o0.y = pk2bf(oa0[2] * inv, oa0[3] * inv);
            o1.x = pk2bf(oa1[0] * inv, oa1[1] * inv);
            o1.y = pk2bf(oa1[2] * inv, oa1[3] * inv);
            *reinterpret_cast<uint2*>(dst + 4 * g) = o0;
            *reinterpret_cast<uint2*>(dst + 16 + 4 * g) = o1;
        }
    }
}

// ---------------------------------------------------------------------------
// K3: MFMA out-projection + bias + residual + LayerNorm (unchanged from R7-R12;
// its single barrier precedes all stores, so no drain issue exists here).
// ---------------------------------------------------------------------------
__global__ __launch_bounds__(256) void out_mfma(
    const ushort* __restrict__ qkv,
    const float* __restrict__ x_don, const float* __restrict__ x_acc,
    const ushort* __restrict__ wtg,
    const float* __restrict__ bo, const float* __restrict__ ln_g, const float* __restrict__ ln_b,
    float* __restrict__ out, int N)
{
    __shared__ ushort wt[128][WTP];
    const int t = threadIdx.x;
    const int lane = t & 63, wid = t >> 6;
    const int r16 = lane & 15, kg = lane >> 4;
    const int r0 = blockIdx.x * 128;                 // row in [0, 2N)
    const int wr0 = r0 + wid * 32;
    const ushort* attb = qkv + (r0 < N ? (size_t)0 : (size_t)2 * N * DIM); // slot0/slot3
    const float* xresb = (r0 < N) ? x_don : x_acc;
    const int rx0 = (r0 < N) ? wr0 : wr0 - N;        // this wave's residual base row

    // ---- stage Wo^T into LDS
    const ushort* wsrc = wtg + ((size_t)3 << 14);
    #pragma unroll
    for (int p = 0; p < 8; ++p) {
        int lin = (p * 256 + t) * 8;
        int c = lin >> 7, k = lin & 127;
        *reinterpret_cast<uint4*>(&wt[c][k]) =
            *reinterpret_cast<const uint4*>(&wsrc[c * DIM + k]);
    }

    // ---- attended A-frags (already bf16), per-lane private
    U8 ab[2][4];
    #pragma unroll
    for (int rt = 0; rt < 2; ++rt)
        #pragma unroll
        for (int ks = 0; ks < 4; ++ks)
            ab[rt][ks].q = *reinterpret_cast<const uint4*>(
                &attb[(size_t)(wr0 + rt * 16 + r16) * DIM + ks * 32 + kg * 8]);

    __syncthreads();                                 // wt ready

    f32x4 acc[2][8];
    #pragma unroll
    for (int i = 0; i < 2; ++i)
        #pragma unroll
        for (int j = 0; j < 8; ++j) acc[i][j] = (f32x4){0.f, 0.f, 0.f, 0.f};

    #pragma unroll
    for (int ks = 0; ks < 4; ++ks)
        #pragma unroll
        for (int ct = 0; ct < 8; ++ct) {
            bf16x8 bfr = *reinterpret_cast<const bf16x8*>(
                &wt[ct * 16 + r16][ks * 32 + kg * 8]);
            acc[0][ct] = __builtin_amdgcn_mfma_f32_16x16x32_bf16(ab[0][ks].v, bfr, acc[0][ct], 0, 0, 0);
            acc[1][ct] = __builtin_amdgcn_mfma_f32_16x16x32_bf16(ab[1][ks].v, bfr, acc[1][ct], 0, 0, 0);
        }

    float bo8[8], g8[8], be8[8];
    #pragma unroll
    for (int ct = 0; ct < 8; ++ct) {
        int c = ct * 16 + r16;
        bo8[ct] = bo[c]; g8[ct] = ln_g[c]; be8[ct] = ln_b[c];
    }

    #pragma unroll
    for (int rt = 0; rt < 2; ++rt) {
        #pragma unroll
        for (int j = 0; j < 4; ++j) {
            int rl = rt * 16 + kg * 4 + j;           // VERIFIED: D row -> att-row (wave-local)
            const float* resr = &xresb[(size_t)(rx0 + rl) * DIM];
            float y[8];
            float s = 0.f, ss = 0.f;
            #pragma unroll
            for (int ct = 0; ct < 8; ++ct) {
                float v = acc[rt][ct][j] + bo8[ct] + resr[ct * 16 + r16];
                y[ct] = v; s += v; ss += v * v;
            }
            #pragma unroll
            for (int mk2 = 1; mk2 < 16; mk2 <<= 1) {
                s  += __shfl_xor(s, mk2);
                ss += __shfl_xor(ss, mk2);
            }
            float mu   = s * (1.f / 128.f);
            float var  = ss * (1.f / 128.f) - mu * mu;
            float rinv = rsqrtf(var + LN_EPS);
            #pragma unroll
            for (int ct = 0; ct < 8; ++ct)
                out[(size_t)(wr0 + rl) * DIM + ct * 16 + r16] =
                    (y[ct] - mu) * rinv * g8[ct] + be8[ct];
        }
    }
}

// ---------------------------------------------------------------------------
extern "C" void kernel_launch(void* const* d_in, const int* in_sizes, int n_in,
                              void* d_out, int out_size, void* d_ws, size_t ws_size,
                              hipStream_t stream)
{
    const float* x_don = (const float*)d_in[0];
    const float* x_acc = (const float*)d_in[1];
    const float* Wq = (const float*)d_in[2];  const float* bq = (const float*)d_in[3];
    const float* Wk = (const float*)d_in[4];  const float* bk = (const float*)d_in[5];
    const float* Wv = (const float*)d_in[6];  const float* bv = (const float*)d_in[7];
    const float* Wo = (const float*)d_in[8];  const float* bo = (const float*)d_in[9];
    const float* ln_g = (const float*)d_in[10]; const float* ln_b = (const float*)d_in[11];
    const int* batch_don = (const int*)d_in[12];
    const int* batch_acc = (const int*)d_in[13];
    const int N = in_sizes[0] / DIM;          // 65536
    float* out = (float*)d_out;

    char* ws = (char*)d_ws;
    int* starts = (int*)ws;                           // 2*NB ints
    int* counts = starts + 2 * NB;                    // 2*NB ints
    ushort* qkv = (ushort*)(ws + 16384);              // 6 x N*DIM bf16 (96MB)
    ushort* wtg = (ushort*)(ws + 16384 + (size_t)6 * N * DIM * 2);  // 4 x 16384 bf16

    setup_kernel<<<256, 256, 0, stream>>>(Wq, Wk, Wv, Wo, wtg,
                                          batch_don, batch_acc, starts, counts, N);

    dim3 gproj(N / 128, 2);
    proj_mfma<<<gproj, 256, 0, stream>>>(x_don, x_acc, wtg, bq, bk, bv, qkv, N);

    dim3 gattn(NB, 2, NH);
    attn_mfma<<<gattn, 64, 0, stream>>>(qkv, starts, counts, N);

    out_mfma<<<(2 * N) / 128, 256, 0, stream>>>(qkv, x_don, x_acc, wtg,
                                                bo, ln_g, ln_b, out, N);
}